// Round 5
// baseline (101.426 us; speedup 1.0000x reference)
//
#include <hip/hip_runtime.h>
#include <hip/hip_bf16.h>

// out[b,d,r] = sum_c p[b,c] * softmax_d( x[b,:] @ W[:, c*8+d, r] + bias[c,d,r] )
// B=16384, F=128, C=8, R=64.  bf16 MFMA 16x16x32, fully fused.
//
// R14->R15: R14 (~35us fused, est.) is LDS-read-BW bound: M=16/wave means
// each B-fragment ds_read_b128 feeds ONE MFMA (16 FLOP/B) -> 512KB/CU/c
// ~ 6kcyc, x8c ~ 20us of LDS reads.  R15 halves that with m=2 (32 rows/
// wave, each B-read feeds 2 MFMAs) while keeping EVERYTHING that R11/R12
// proved must not change: the [1d x 16r] column packing (in-lane softmax
// over 8 d-accs, zero shuffles, full 64B-line stores), the R10 prepass,
// and R14's pipeline (ONE barrier/c, double-buffered 2x32KB stage issued
// right after the barrier).  The register growth (acc 64 AGPR + O 64 +
// afr 32 ~ 190) is absorbed by sizing for it instead of fighting it:
// 256-thr blocks, launch_bounds(256,2) (<=256-reg tier, no spills), grid
// 512 = exactly 2 blocks/CU = 2 waves/SIMD fully resident, LDS 128KB/CU.
// w-major grid keeps all 4 r-chunks of a row-group on one XCD.

#define B_ROWS   16384
#define F_DIM    128
#define NCOL     4096      // C*C*R
#define OUT_STRIDE 512     // C*R
#define LOG2E    1.44269504088896340736f

typedef __bf16 bf16x8 __attribute__((ext_vector_type(8)));
typedef float  f32x4  __attribute__((ext_vector_type(4)));

#define AS1(p) ((const __attribute__((address_space(1))) unsigned int*)(p))
#define AS3(p) ((__attribute__((address_space(3))) unsigned int*)(p))

// ---------------------------------------------------------------------------
// Prepass: W fp32 (128 x 4096 row-major) -> bf16 MFMA B-fragments.
// Tile t in [0,256) covers cols t*16..t*16+16; fragment (t,kk) holds
// k = kk*32 + (lane>>4)*8 + j, n = t*16 + (lane&15), at wf[(t*4+kk)*512].
// (identical to the proven R10/R14 prepass)
// ---------------------------------------------------------------------------
__global__ void wconv_kernel(const float* __restrict__ W, __bf16* __restrict__ wf) {
    int f    = blockIdx.x * 256 + threadIdx.x;  // 0..65535
    int lane = f & 63;
    int tkk  = f >> 6;
    int t    = tkk >> 2;
    int kk   = tkk & 3;
    int kbase = kk * 32 + (lane >> 4) * 8;
    int n     = t * 16 + (lane & 15);
    bf16x8 frag;
#pragma unroll
    for (int j = 0; j < 8; ++j)
        frag[j] = (__bf16)W[(kbase + j) * NCOL + n];
    *(bf16x8*)(wf + (size_t)f * 8) = frag;
}

// ---------------------------------------------------------------------------
// Fused GEMM + bias + softmax(d) + p-contraction.
// Block: 256 thr (4 waves), 128 batch rows, one 16-r chunk w = blockIdx>>7.
// Wave ww owns rows b0..b0+32 (2 m-tiles: every B ds_read feeds 2 MFMAs).
// Per c: 32 fragments (8 d x 4 kk, 32 KB) double-buffer-staged (wave ww
// stages d = 2ww, 2ww+1); each wave reads all 32 (block-shared).
// acc[m][d] (64 AGPR) ; softmax over d is in-lane (8 exp2, 7-add tree,
// 1 rcp, 8 fma per (m,jj)); C-in = bias.
// C/D layout: col=lane&15 -> r, row=quad*4+jj -> batch row.
// ---------------------------------------------------------------------------
__global__ __launch_bounds__(256, 2)
void fused_kernel(const float* __restrict__ x, const float* __restrict__ p,
                  const float* __restrict__ bias, const __bf16* __restrict__ wf,
                  float* __restrict__ out) {
    __shared__ __align__(16) char lds[65536];   // 2 x (32 fragments = 32 KB)

    const int lane = threadIdx.x & 63;
    const int ww   = threadIdx.x >> 6;   // wave 0..3
    const int quad = lane >> 4;
    const int l15  = lane & 15;
    const int w    = blockIdx.x >> 7;    // r-chunk 0..3 (w-major: XCD = g%8)
    const int g    = blockIdx.x & 127;   // row-group
    const int b0   = g * 128 + ww * 32;

    // ---- prologue: stage c=0 into buffer 0 (wave ww stages d=2ww,2ww+1) ---
    {
#pragma unroll
        for (int j = 0; j < 8; ++j) {
            int d  = ww * 2 + (j >> 2);
            int kk = j & 3;
            int gf = d * 16 + w * 4 + kk;            // c=0
            __builtin_amdgcn_global_load_lds(
                AS1(wf + (size_t)gf * 512 + lane * 8),
                AS3(lds + (d * 4 + kk) * 1024), 16, 0, 0);
        }
    }

    // A fragments: afr[m][kk][j] = x_bf16[b0+m*16+l15][kk*32 + quad*8 + j]
    bf16x8 afr[2][4];
#pragma unroll
    for (int m = 0; m < 2; ++m) {
        const float* xr = x + (size_t)(b0 + m * 16 + l15) * F_DIM + quad * 8;
#pragma unroll
        for (int kk = 0; kk < 4; ++kk) {
            float4 lo = *(const float4*)(xr + kk * 32);
            float4 hi = *(const float4*)(xr + kk * 32 + 4);
            bf16x8 f;
            f[0] = (__bf16)lo.x; f[1] = (__bf16)lo.y;
            f[2] = (__bf16)lo.z; f[3] = (__bf16)lo.w;
            f[4] = (__bf16)hi.x; f[5] = (__bf16)hi.y;
            f[6] = (__bf16)hi.z; f[7] = (__bf16)hi.w;
            afr[m][kk] = f;
        }
    }

    float O[2][8][4] = {};   // [m][d][jj] output accumulator over c

#pragma unroll 1
    for (int c = 0; c < 8; ++c) {
        // barrier: stage(c) landed (its loads had the whole previous compute
        // phase in flight) AND all waves done reading buf[(c+1)&1].
        __syncthreads();

        // ---- issue stage(c+1) into the other buffer (hides under compute)
        if (c < 7) {
            char* dst = lds + ((c + 1) & 1) * 32768;
#pragma unroll
            for (int j = 0; j < 8; ++j) {
                int d  = ww * 2 + (j >> 2);
                int kk = j & 3;
                int gf = (c + 1) * 128 + d * 16 + w * 4 + kk;
                __builtin_amdgcn_global_load_lds(
                    AS1(wf + (size_t)gf * 512 + lane * 8),
                    AS3(dst + (d * 4 + kk) * 1024), 16, 0, 0);
            }
        }

        // ---- p and bias loads issued before MFMAs (latency hides under them)
        float pvv[2][4];
#pragma unroll
        for (int m = 0; m < 2; ++m)
#pragma unroll
            for (int jj = 0; jj < 4; ++jj)
                pvv[m][jj] = p[(size_t)(b0 + m * 16 + quad * 4 + jj) * 8 + c];

        float bvl[8];
#pragma unroll
        for (int d = 0; d < 8; ++d)
            bvl[d] = bias[(c * 8 + d) * 64 + w * 16 + l15];

        // C-in = bias (row-invariant per column)
        f32x4 acc[2][8];
#pragma unroll
        for (int d = 0; d < 8; ++d) {
            f32x4 binit = {bvl[d], bvl[d], bvl[d], bvl[d]};
            acc[0][d] = binit;
            acc[1][d] = binit;
        }

        const char* buf = lds + (c & 1) * 32768;
#pragma unroll
        for (int kk = 0; kk < 4; ++kk) {
#pragma unroll
            for (int d = 0; d < 8; ++d) {
                bf16x8 bfr = *(const bf16x8*)(buf + (d * 4 + kk) * 1024 + lane * 16);
                acc[0][d] = __builtin_amdgcn_mfma_f32_16x16x32_bf16(
                                afr[0][kk], bfr, acc[0][d], 0, 0, 0);
                acc[1][d] = __builtin_amdgcn_mfma_f32_16x16x32_bf16(
                                afr[1][kk], bfr, acc[1][d], 0, 0, 0);
            }
        }

        // ---- in-lane softmax over d + p-weighted accumulate ---------------
#pragma unroll
        for (int m = 0; m < 2; ++m) {
#pragma unroll
            for (int jj = 0; jj < 4; ++jj) {
                float e[8];
#pragma unroll
                for (int d = 0; d < 8; ++d)
                    e[d] = __builtin_amdgcn_exp2f(acc[m][d][jj] * LOG2E);
                float s01 = e[0] + e[1], s23 = e[2] + e[3];
                float s45 = e[4] + e[5], s67 = e[6] + e[7];
                float s = (s01 + s23) + (s45 + s67);
                float scale = pvv[m][jj] * __builtin_amdgcn_rcpf(s);
#pragma unroll
                for (int d = 0; d < 8; ++d)
                    O[m][d][jj] = __builtin_fmaf(e[d], scale, O[m][d][jj]);
            }
        }
        // no second barrier: next iteration's __syncthreads covers the
        // write-after-read hazard on buf[(c+1)&1].
    }

    // ---- stores: out[b, d*64 + w*16 + l15] — 64B per quad, full lines -----
#pragma unroll
    for (int m = 0; m < 2; ++m)
#pragma unroll
        for (int jj = 0; jj < 4; ++jj) {
            float* orow = out + (size_t)(b0 + m * 16 + quad * 4 + jj) * OUT_STRIDE
                          + w * 16 + l15;
#pragma unroll
            for (int d = 0; d < 8; ++d)
                orow[d * 64] = O[m][d][jj];
        }
}

extern "C" void kernel_launch(void* const* d_in, const int* in_sizes, int n_in,
                              void* d_out, int out_size, void* d_ws, size_t ws_size,
                              hipStream_t stream) {
    const float* x    = (const float*)d_in[0];   // (16384, 128)
    const float* p    = (const float*)d_in[1];   // (16384, 8)
    const float* W    = (const float*)d_in[2];   // (128, 64, 64)
    const float* bias = (const float*)d_in[3];   // (8, 8, 64)
    float* out = (float*)d_out;                  // (16384, 8, 64)
    __bf16* wf = (__bf16*)d_ws;                  // 1 MB bf16 fragments

    wconv_kernel<<<dim3(256), dim3(256), 0, stream>>>(W, wf);
    fused_kernel<<<dim3(512), dim3(256), 0, stream>>>(x, p, bias, wf, out);
}

// Round 6
// 100.978 us; speedup vs baseline: 1.0044x; 1.0044x over previous
//
#include <hip/hip_runtime.h>
#include <hip/hip_bf16.h>

// out[b,d,r] = sum_c p[b,c] * softmax_d( x[b,:] @ W[:, c*8+d, r] + bias[c,d,r] )
// B=16384, F=128, C=8, R=64.  bf16 MFMA 16x16x32, fully fused.
//
// R15->R16: m=2 closed for good -- at 32 rows/wave total waves = 2048 = 8/CU,
// so halved LDS traffic is exactly cancelled by halved occupancy (measured:
// R14 99.4 ~= R15 101.4).  R14's residual gap to the ~23us overlap floor is
// phase CONVOY: 8 barrier-locked waves/block burst through {ds_read->MFMA->
// softmax} together with only 2 independent blocks/CU to anti-phase.  R16
// maximizes phase diversity at fixed 16 waves/CU:
//  - 256-thr/4-wave blocks, grid 1024 -> 4 independent blocks/CU.
//  - half-c staging (16KB chunks: d0-3 / d4-7), ring-2 = 32KB LDS/block so
//    4 blocks fit in 128KB/CU; 16 finer phases interleave pipes at 2x grain.
//  - LOG2E folded into prepass (W*log2e, bias*log2e) -> softmax is
//    exp2(acc) directly (exact: 2^(x*log2e) = e^x); kills 32 vmul/wave/c.
//  - s_setprio(1) around the MFMA cluster (T5: MFMA/VALU role diversity).
//  - h compile-time in both phase bodies (no runtime acc indexing).

#define B_ROWS   16384
#define F_DIM    128
#define NCOL     4096      // C*C*R
#define OUT_STRIDE 512     // C*R
#define LOG2E    1.44269504088896340736f

typedef __bf16 bf16x8 __attribute__((ext_vector_type(8)));
typedef float  f32x4  __attribute__((ext_vector_type(4)));

#define AS1(p) ((const __attribute__((address_space(1))) unsigned int*)(p))
#define AS3(p) ((__attribute__((address_space(3))) unsigned int*)(p))

// ---------------------------------------------------------------------------
// Prepass: W fp32 (128 x 4096 row-major) -> bf16 MFMA B-fragments, PRE-SCALED
// by log2(e) so the fused softmax uses exp2 directly.  Also emits
// bias_s = bias * log2(e) (4096 floats) after the fragments.
// Tile t in [0,256) covers cols t*16..t*16+16; fragment (t,kk) holds
// k = kk*32 + (lane>>4)*8 + j, n = t*16 + (lane&15), at wf[(t*4+kk)*512].
// ---------------------------------------------------------------------------
__global__ void wconv_kernel(const float* __restrict__ W,
                             const float* __restrict__ bias,
                             __bf16* __restrict__ wf,
                             float* __restrict__ bias_s) {
    int f    = blockIdx.x * 256 + threadIdx.x;  // 0..65535
    int lane = f & 63;
    int tkk  = f >> 6;
    int t    = tkk >> 2;
    int kk   = tkk & 3;
    int kbase = kk * 32 + (lane >> 4) * 8;
    int n     = t * 16 + (lane & 15);
    bf16x8 frag;
#pragma unroll
    for (int j = 0; j < 8; ++j)
        frag[j] = (__bf16)(W[(kbase + j) * NCOL + n] * LOG2E);
    *(bf16x8*)(wf + (size_t)f * 8) = frag;
    if (f < NCOL)
        bias_s[f] = bias[f] * LOG2E;
}

// ---------------------------------------------------------------------------
// Fused GEMM + bias + softmax(d) + p-contraction.
// Block: 256 thr (4 waves), 64 batch rows, one 16-r chunk w = blockIdx>>8.
// Wave ww owns rows b0..b0+16 (m=1).  Per c: TWO half-phases (h=0: d0-3,
// h=1: d4-7), each staging 16 fragments (16KB) into ring slot h (wave ww
// stages dd=ww's 4 kk frags); stage(ph+1) issued right after the one
// barrier per phase.  8 in-lane d-accumulators; softmax at h==1 over all 8
// (8 exp2 + 7-add tree + 1 rcp + 8 fma per jj, zero shuffles, zero muls).
// C-in = bias_s.  C/D layout: col=lane&15 -> r, row=quad*4+jj -> batch row.
// ---------------------------------------------------------------------------
__global__ __launch_bounds__(256, 4)
void fused_kernel(const float* __restrict__ x, const float* __restrict__ p,
                  const float* __restrict__ bias_s, const __bf16* __restrict__ wf,
                  float* __restrict__ out) {
    __shared__ __align__(16) char lds[32768];   // 2 ring slots x 16 KB

    const int lane = threadIdx.x & 63;
    const int ww   = threadIdx.x >> 6;   // wave 0..3 (= staged dd)
    const int quad = lane >> 4;
    const int l15  = lane & 15;
    const int w    = blockIdx.x >> 8;    // r-chunk 0..3 (w-major)
    const int g    = blockIdx.x & 255;   // row-group
    const int b0   = g * 64 + ww * 16;

    // ---- prologue: stage phase 0 (c=0, h=0, slot 0) -----------------------
    // fragment gf = c*128 + d*16 + w*4 + kk, here d = ww.
    {
        const __bf16* src = wf + (size_t)(ww * 16 + w * 4) * 512 + lane * 8;
#pragma unroll
        for (int kk = 0; kk < 4; ++kk)
            __builtin_amdgcn_global_load_lds(
                AS1(src + kk * 512),
                AS3(lds + (ww * 4 + kk) * 1024), 16, 0, 0);
    }

    // A fragments: afr[kk][j] = x_bf16[b0+l15][kk*32 + quad*8 + j]
    bf16x8 afr[4];
    {
        const float* xr = x + (size_t)(b0 + l15) * F_DIM + quad * 8;
#pragma unroll
        for (int kk = 0; kk < 4; ++kk) {
            float4 lo = *(const float4*)(xr + kk * 32);
            float4 hi = *(const float4*)(xr + kk * 32 + 4);
            bf16x8 f;
            f[0] = (__bf16)lo.x; f[1] = (__bf16)lo.y;
            f[2] = (__bf16)lo.z; f[3] = (__bf16)lo.w;
            f[4] = (__bf16)hi.x; f[5] = (__bf16)hi.y;
            f[6] = (__bf16)hi.z; f[7] = (__bf16)hi.w;
            afr[kk] = f;
        }
    }

    float O[8][4] = {};   // [d][jj] output accumulator over c
    f32x4 acc[8];
    float pvv[4];

#pragma unroll 1
    for (int c = 0; c < 8; ++c) {
        // =================== phase h=0 (slot 0, d = 0..3) ==================
        {
            // barrier: stage(2c) landed (issued one phase ago) AND all waves
            // done reading slot 0 from the previous c.
            __syncthreads();

            // stage next phase (2c+1): c, h=1 -> slot 1, d = 4+ww
            {
                const __bf16* src =
                    wf + (size_t)(c * 128 + (4 + ww) * 16 + w * 4) * 512 + lane * 8;
#pragma unroll
                for (int kk = 0; kk < 4; ++kk)
                    __builtin_amdgcn_global_load_lds(
                        AS1(src + kk * 512),
                        AS3(lds + 16384 + (ww * 4 + kk) * 1024), 16, 0, 0);
            }

            // p for this c (consumed in h=1's softmax: 2 phases of latency)
#pragma unroll
            for (int jj = 0; jj < 4; ++jj)
                pvv[jj] = p[(size_t)(b0 + quad * 4 + jj) * 8 + c];

            float bvl[4];
#pragma unroll
            for (int dd = 0; dd < 4; ++dd)
                bvl[dd] = bias_s[(c * 8 + dd) * 64 + w * 16 + l15];
#pragma unroll
            for (int dd = 0; dd < 4; ++dd) {
                f32x4 binit = {bvl[dd], bvl[dd], bvl[dd], bvl[dd]};
                acc[dd] = binit;
            }

            __builtin_amdgcn_s_setprio(1);
#pragma unroll
            for (int kk = 0; kk < 4; ++kk)
#pragma unroll
                for (int dd = 0; dd < 4; ++dd) {
                    bf16x8 bfr = *(const bf16x8*)(lds + (dd * 4 + kk) * 1024 + lane * 16);
                    acc[dd] = __builtin_amdgcn_mfma_f32_16x16x32_bf16(
                                  afr[kk], bfr, acc[dd], 0, 0, 0);
                }
            __builtin_amdgcn_s_setprio(0);
        }

        // =================== phase h=1 (slot 1, d = 4..7) ==================
        {
            // barrier: stage(2c+1) landed AND all waves done with slot 1.
            __syncthreads();

            // stage next phase (2c+2): c+1, h=0 -> slot 0, d = ww
            if (c < 7) {
                const __bf16* src =
                    wf + (size_t)((c + 1) * 128 + ww * 16 + w * 4) * 512 + lane * 8;
#pragma unroll
                for (int kk = 0; kk < 4; ++kk)
                    __builtin_amdgcn_global_load_lds(
                        AS1(src + kk * 512),
                        AS3(lds + (ww * 4 + kk) * 1024), 16, 0, 0);
            }

            float bvl[4];
#pragma unroll
            for (int dd = 0; dd < 4; ++dd)
                bvl[dd] = bias_s[(c * 8 + 4 + dd) * 64 + w * 16 + l15];
#pragma unroll
            for (int dd = 0; dd < 4; ++dd) {
                f32x4 binit = {bvl[dd], bvl[dd], bvl[dd], bvl[dd]};
                acc[4 + dd] = binit;
            }

            __builtin_amdgcn_s_setprio(1);
#pragma unroll
            for (int kk = 0; kk < 4; ++kk)
#pragma unroll
                for (int dd = 0; dd < 4; ++dd) {
                    bf16x8 bfr = *(const bf16x8*)(lds + 16384 + (dd * 4 + kk) * 1024 + lane * 16);
                    acc[4 + dd] = __builtin_amdgcn_mfma_f32_16x16x32_bf16(
                                      afr[kk], bfr, acc[4 + dd], 0, 0, 0);
                }
            __builtin_amdgcn_s_setprio(0);

            // ---- softmax over all 8 d + p-weighted accumulate (exp2 direct)
#pragma unroll
            for (int jj = 0; jj < 4; ++jj) {
                float e[8];
#pragma unroll
                for (int d = 0; d < 8; ++d)
                    e[d] = __builtin_amdgcn_exp2f(acc[d][jj]);
                float s01 = e[0] + e[1], s23 = e[2] + e[3];
                float s45 = e[4] + e[5], s67 = e[6] + e[7];
                float s = (s01 + s23) + (s45 + s67);
                float scale = pvv[jj] * __builtin_amdgcn_rcpf(s);
#pragma unroll
                for (int d = 0; d < 8; ++d)
                    O[d][jj] = __builtin_fmaf(e[d], scale, O[d][jj]);
            }
        }
    }

    // ---- stores: out[b, d*64 + w*16 + l15] — 64B per quad, full lines -----
#pragma unroll
    for (int jj = 0; jj < 4; ++jj) {
        float* orow = out + (size_t)(b0 + quad * 4 + jj) * OUT_STRIDE + w * 16 + l15;
#pragma unroll
        for (int d = 0; d < 8; ++d)
            orow[d * 64] = O[d][jj];
    }
}

extern "C" void kernel_launch(void* const* d_in, const int* in_sizes, int n_in,
                              void* d_out, int out_size, void* d_ws, size_t ws_size,
                              hipStream_t stream) {
    const float* x    = (const float*)d_in[0];   // (16384, 128)
    const float* p    = (const float*)d_in[1];   // (16384, 8)
    const float* W    = (const float*)d_in[2];   // (128, 64, 64)
    const float* bias = (const float*)d_in[3];   // (8, 8, 64)
    float* out = (float*)d_out;                  // (16384, 8, 64)
    __bf16* wf     = (__bf16*)d_ws;              // 1 MB bf16 fragments
    float*  bias_s = (float*)((char*)d_ws + (1 << 20));  // 16 KB scaled bias

    wconv_kernel<<<dim3(256), dim3(256), 0, stream>>>(W, bias, wf, bias_s);
    fused_kernel<<<dim3(1024), dim3(256), 0, stream>>>(x, p, bias_s, wf, out);
}